// Round 1
// baseline (218.878 us; speedup 1.0000x reference)
//
#include <hip/hip_runtime.h>
#include <hip/hip_bf16.h>

typedef unsigned short u16;
typedef __attribute__((ext_vector_type(8))) short short8;
typedef __attribute__((ext_vector_type(4))) float f32x4;

#define HID 128
#define WNUMEL 3072
#define OUTD 144

// ---------- W2 reorder: bf16, swizzled so B-fragments are lane-linear ----------
// dest flat = ((t*4+s)*64 + lane)*8 + i, lane = c + 16*h, element = W2[32s+8h+i][16t+c]
__global__ void k_w2s(const float* __restrict__ W2, __hip_bfloat16* __restrict__ W2s) {
  int t = blockIdx.x * 256 + threadIdx.x;           // < 128*3072 = 393216
  int i = t & 7, lane = (t >> 3) & 63, s = (t >> 9) & 3, tt = t >> 11;
  int c = lane & 15, h = lane >> 4;
  int k = 32 * s + 8 * h + i;
  int n = 16 * tt + c;
  W2s[t] = __float2bfloat16(W2[k * WNUMEL + n]);
}

// ---------- MLP: h2 = silu(es@W1+b1) * 0.125, stored bf16 pre-swizzled ----------
__global__ void k_mlp(const float* __restrict__ es, const float* __restrict__ W1,
                      const float* __restrict__ b1, __hip_bfloat16* __restrict__ h2s, int E) {
  __shared__ float esl[2][32];
  int tid = threadIdx.x;
  int e0 = blockIdx.x * 2;
  int eloc = tid >> 7, h = tid & 127;
  if (tid < 64) {
    int e = e0 + (tid >> 5);
    esl[tid >> 5][tid & 31] = (e < E) ? es[e * 32 + (tid & 31)] : 0.f;
  }
  __syncthreads();
  int e = e0 + eloc;
  if (e < E) {
    float acc = b1[h];
#pragma unroll
    for (int i = 0; i < 32; ++i) acc = fmaf(esl[eloc][i], W1[i * HID + h], acc);
    float sg = 1.f / (1.f + expf(-acc));
    float z = acc * sg * 0.125f;                    // fold 1/sqrt(64)
    int s = h >> 5, hh = (h >> 3) & 3, i = h & 7;
    int lane = (e & 15) + 16 * hh, eblk = e >> 4;
    h2s[((eblk * 4 + s) * 64 + lane) * 8 + i] = __float2bfloat16(z);
  }
}

// ---------- prep: gather x, spherical harmonics, count histogram ----------
__global__ void k_prep(const float* __restrict__ hsrc, const float* __restrict__ ev,
                       const int* __restrict__ src, const int* __restrict__ dst,
                       float* __restrict__ xg, float* __restrict__ shb,
                       float* __restrict__ cnt, int E) {
  int lane = threadIdx.x & 63;
  int e = blockIdx.x * 4 + (threadIdx.x >> 6);
  if (e >= E) return;
  int s = src[e];
  xg[e * 64 + lane] = hsrc[s * 64 + lane];
  if (lane < 9) {
    float vx = ev[e * 3 + 0], vy = ev[e * 3 + 1], vz = ev[e * 3 + 2];
    float nrm = fmaxf(sqrtf(vx * vx + vy * vy + vz * vz), 1e-9f);
    float x = vx / nrm, y = vy / nrm, z = vz / nrm;
    const float SQ3 = 1.7320508075688772f, SQ5 = 2.2360679774997896f,
                SQ15 = 3.872983346207417f;
    float v;
    switch (lane) {
      case 0: v = 1.f; break;
      case 1: v = SQ3 * x; break;
      case 2: v = SQ3 * y; break;
      case 3: v = SQ3 * z; break;
      case 4: v = SQ15 * x * y; break;
      case 5: v = SQ15 * y * z; break;
      case 6: v = 0.5f * SQ5 * (3.f * z * z - 1.f); break;
      case 7: v = SQ15 * x * z; break;
      default: v = 0.5f * SQ15 * (x * x - y * y); break;
    }
    shb[e * 9 + lane] = v;
  }
  if (lane == 9) atomicAdd(&cnt[dst[e]], 1.f);
}

// ---------- fused GEMM + x-contraction + sh scatter ----------
// block = 256 thr (4 waves), 128 edges/block; wave w owns edges [w*32, w*32+32)
__global__ __launch_bounds__(256, 2) void k_gemm(
    const u16* __restrict__ h2s, const u16* __restrict__ W2s,
    const float* __restrict__ xg, const float* __restrict__ shb,
    const float* __restrict__ b2, const int* __restrict__ dst,
    float* __restrict__ out, int E) {
  __shared__ u16 ldsB[2][8192];          // 2 x 16 KB: chunk = 4 N-tiles
  __shared__ float xlds[128 * 64];       // 32 KB
  const int tid = threadIdx.x;
  const int lane = tid & 63, wave = tid >> 6;
  const int blk = blockIdx.x;

  // stage x (block's 128 edges x 64) — linear copy, coalesced
#pragma unroll
  for (int r = 0; r < 8; ++r)
    ((float4*)xlds)[r * 256 + tid] = ((const float4*)(xg + blk * 8192))[r * 256 + tid];

  // A-fragments: register-resident for the whole N loop (2 M-tiles x 4 k-steps)
  short8 af[2][4];
#pragma unroll
  for (int m = 0; m < 2; ++m)
#pragma unroll
    for (int s = 0; s < 4; ++s) {
      int eblk = blk * 8 + wave * 2 + m;
      af[m][s] = *(const short8*)(h2s + ((eblk * 4 + s) * 64 + lane) * 8);
    }

  float feat[2][3][4] = {};

  // preload chunk 0 into regs
  int4 st[4];
#pragma unroll
  for (int r = 0; r < 4; ++r) st[r] = ((const int4*)W2s)[r * 256 + tid];

#pragma unroll
  for (int l3 = 0; l3 < 3; ++l3) {
    for (int cc = 0; cc < 16; ++cc) {
      const int c = l3 * 16 + cc;
      // write chunk c (regs -> LDS), then prefetch chunk c+1
#pragma unroll
      for (int r = 0; r < 4; ++r) ((int4*)ldsB[c & 1])[r * 256 + tid] = st[r];
      if (c + 1 < 48) {
#pragma unroll
        for (int r = 0; r < 4; ++r)
          st[r] = ((const int4*)W2s)[(c + 1) * 1024 + r * 256 + tid];
      }
      __syncthreads();
      const u16* B = ldsB[c & 1];
#pragma unroll
      for (int tt = 0; tt < 4; ++tt) {
        const int u = cc * 4 + tt;
        short8 bf[4];
#pragma unroll
        for (int s = 0; s < 4; ++s)
          bf[s] = *(const short8*)(B + ((tt * 4 + s) * 64 + lane) * 8);
        float b2v = 0.125f * b2[(c * 4 + tt) * 16 + (lane & 15)];
#pragma unroll
        for (int m = 0; m < 2; ++m) {
          f32x4 acc = {0.f, 0.f, 0.f, 0.f};
#pragma unroll
          for (int s = 0; s < 4; ++s)
            acc = __builtin_amdgcn_mfma_f32_16x16x32_bf16(af[m][s], bf[s], acc, 0, 0, 0);
#pragma unroll
          for (int j = 0; j < 4; ++j) {
            float wv = acc[j] + b2v;
            int eloc = wave * 32 + m * 16 + (lane >> 4) * 4 + j;
            feat[m][l3][j] += xlds[eloc * 64 + u] * wv;
          }
        }
      }
    }
  }

  // epilogue: msg = feat (x) sh, e3nn flatten v*deg+m, atomic scatter
#pragma unroll
  for (int m = 0; m < 2; ++m)
#pragma unroll
    for (int j = 0; j < 4; ++j) {
      int e = blk * 128 + wave * 32 + m * 16 + (lane >> 4) * 4 + j;
      if (e < E) {
        int d = dst[e];
        const float* sp = shb + e * 9;
        float* ob = out + d * OUTD;
        int v = lane & 15;
        atomicAdd(ob + v, feat[m][0][j]);                       // l=0, sh0 == 1
#pragma unroll
        for (int mm = 0; mm < 3; ++mm)
          atomicAdd(ob + 16 + v * 3 + mm, feat[m][1][j] * sp[1 + mm]);
#pragma unroll
        for (int mm = 0; mm < 5; ++mm)
          atomicAdd(ob + 64 + v * 5 + mm, feat[m][2][j] * sp[4 + mm]);
      }
    }
}

// ---------- final mean ----------
__global__ void k_divc(float* __restrict__ out, const float* __restrict__ cnt, int total) {
  int i = blockIdx.x * 256 + threadIdx.x;
  if (i < total) out[i] /= fmaxf(cnt[i / OUTD], 1.f);
}

extern "C" void kernel_launch(void* const* d_in, const int* in_sizes, int n_in,
                              void* d_out, int out_size, void* d_ws, size_t ws_size,
                              hipStream_t stream) {
  const float* h_src        = (const float*)d_in[0];
  const float* edge_vec     = (const float*)d_in[1];
  const float* edge_scalars = (const float*)d_in[2];
  const float* W1           = (const float*)d_in[3];
  const float* b1           = (const float*)d_in[4];
  const float* W2           = (const float*)d_in[5];
  const float* b2           = (const float*)d_in[6];
  const int*   src_idx      = (const int*)d_in[7];
  const int*   dst_idx      = (const int*)d_in[8];

  const int E = in_sizes[1] / 3;
  const int n_dst = out_size / OUTD;
  const int nblk = (E + 127) / 128;
  const size_t E_pad = (size_t)nblk * 128;

  char* w = (char*)d_ws;
  auto al = [](size_t x) { return (x + 255) & ~(size_t)255; };
  size_t o = 0;
  float* xg  = (float*)(w + o);              o += al(E_pad * 64 * 4);
  float* shb = (float*)(w + o);              o += al(E_pad * 9 * 4);
  __hip_bfloat16* h2s = (__hip_bfloat16*)(w + o); o += al(E_pad * 128 * 2);
  __hip_bfloat16* W2s = (__hip_bfloat16*)(w + o); o += al((size_t)128 * 3072 * 2);
  float* cnt = (float*)(w + o);              o += al((size_t)n_dst * 4);

  hipMemsetAsync(d_out, 0, (size_t)out_size * 4, stream);
  hipMemsetAsync(cnt, 0, (size_t)n_dst * 4, stream);

  k_w2s <<<(128 * WNUMEL) / 256, 256, 0, stream>>>(W2, W2s);
  k_mlp <<<(E + 1) / 2, 256, 0, stream>>>(edge_scalars, W1, b1, h2s, E);
  k_prep<<<(E + 3) / 4, 256, 0, stream>>>(h_src, edge_vec, src_idx, dst_idx, xg, shb, cnt, E);
  k_gemm<<<nblk, 256, 0, stream>>>((const u16*)h2s, (const u16*)W2s, xg, shb, b2,
                                   dst_idx, (float*)d_out, E);
  k_divc<<<(out_size + 255) / 256, 256, 0, stream>>>((float*)d_out, cnt, out_size);
}

// Round 2
// 215.058 us; speedup vs baseline: 1.0178x; 1.0178x over previous
//
#include <hip/hip_runtime.h>
#include <hip/hip_bf16.h>

typedef unsigned short u16;
typedef __attribute__((ext_vector_type(8))) short short8;
typedef __attribute__((ext_vector_type(4))) float f32x4;

#define HID 128
#define WNUMEL 3072
#define OUTD 144

// ---------- W2 reorder: bf16, swizzled so B-fragments are lane-linear ----------
// dest flat = ((t*4+s)*64 + lane)*8 + i, lane = c + 16*h, element = W2[32s+8h+i][16t+c]
__global__ void k_w2s(const float* __restrict__ W2, __hip_bfloat16* __restrict__ W2s) {
  int t = blockIdx.x * 256 + threadIdx.x;           // < 128*3072 = 393216
  int i = t & 7, lane = (t >> 3) & 63, s = (t >> 9) & 3, tt = t >> 11;
  int c = lane & 15, h = lane >> 4;
  int k = 32 * s + 8 * h + i;
  int n = 16 * tt + c;
  W2s[t] = __float2bfloat16(W2[k * WNUMEL + n]);
}

// ---------- MLP: h2 = silu(es@W1+b1) * 0.125, stored bf16 pre-swizzled ----------
// 8 edges per block now (was 2) — fewer blocks, W1 L1-resident re-reads
__global__ void k_mlp(const float* __restrict__ es, const float* __restrict__ W1,
                      const float* __restrict__ b1, __hip_bfloat16* __restrict__ h2s, int E) {
  __shared__ float esl[8][32];
  int tid = threadIdx.x;
  int e0 = blockIdx.x * 8;
  {
    int e = e0 + (tid >> 5);
    esl[tid >> 5][tid & 31] = (e < E) ? es[e * 32 + (tid & 31)] : 0.f;
  }
  __syncthreads();
  int h = tid & 127;
  float bh = b1[h];
#pragma unroll
  for (int r = 0; r < 4; ++r) {
    int eloc = (tid >> 7) + r * 2;
    int e = e0 + eloc;
    if (e < E) {
      float acc = bh;
#pragma unroll
      for (int i = 0; i < 32; ++i) acc = fmaf(esl[eloc][i], W1[i * HID + h], acc);
      float sg = 1.f / (1.f + expf(-acc));
      float z = acc * sg * 0.125f;                  // fold 1/sqrt(64)
      int s = h >> 5, hh = (h >> 3) & 3, i = h & 7;
      int lane = (e & 15) + 16 * hh, eblk = e >> 4;
      h2s[((eblk * 4 + s) * 64 + lane) * 8 + i] = __float2bfloat16(z);
    }
  }
}

// ---------- prep: gather x, spherical harmonics, count histogram ----------
__global__ void k_prep(const float* __restrict__ hsrc, const float* __restrict__ ev,
                       const int* __restrict__ src, const int* __restrict__ dst,
                       float* __restrict__ xg, float* __restrict__ shb,
                       float* __restrict__ cnt, int E) {
  int lane = threadIdx.x & 63;
  int e = blockIdx.x * 4 + (threadIdx.x >> 6);
  if (e >= E) return;
  int s = src[e];
  xg[e * 64 + lane] = hsrc[s * 64 + lane];
  if (lane < 9) {
    float vx = ev[e * 3 + 0], vy = ev[e * 3 + 1], vz = ev[e * 3 + 2];
    float nrm = fmaxf(sqrtf(vx * vx + vy * vy + vz * vz), 1e-9f);
    float x = vx / nrm, y = vy / nrm, z = vz / nrm;
    const float SQ3 = 1.7320508075688772f, SQ5 = 2.2360679774997896f,
                SQ15 = 3.872983346207417f;
    float v;
    switch (lane) {
      case 0: v = 1.f; break;
      case 1: v = SQ3 * x; break;
      case 2: v = SQ3 * y; break;
      case 3: v = SQ3 * z; break;
      case 4: v = SQ15 * x * y; break;
      case 5: v = SQ15 * y * z; break;
      case 6: v = 0.5f * SQ5 * (3.f * z * z - 1.f); break;
      case 7: v = SQ15 * x * z; break;
      default: v = 0.5f * SQ15 * (x * x - y * y); break;
    }
    shb[e * 9 + lane] = v;
  }
  if (lane == 9) atomicAdd(&cnt[dst[e]], 1.f);
}

// ---------- fused GEMM + x-contraction + sh scatter (v2) ----------
// grid = (E/64, 3):  blockIdx.x = 64-edge block, blockIdx.y = l-path.
// 4 waves; wave w owns N-tiles [w*16, w*16+16) of this l-path (disjoint B reads,
// read straight from global/L2 — W2s is 786 KB, L2-resident; NO main-loop barriers).
// A-fragments (all 64 edges x K=128) live in registers for the whole kernel.
__global__ __launch_bounds__(256, 3) void k_gemm(
    const u16* __restrict__ h2s, const u16* __restrict__ W2s,
    const float* __restrict__ xg, const float* __restrict__ shb,
    const float* __restrict__ b2, const int* __restrict__ dst,
    float* __restrict__ out, int E) {
  __shared__ float lds[4160];          // 16.25 KB: xT[64u][64e] then fl[4][1040]
  float* xT = lds;
  float* fl = lds;
  const int tid = threadIdx.x, lane = tid & 63, wave = tid >> 6;
  const int blk = blockIdx.x, l3 = blockIdx.y;
  const int c = lane & 15, g = lane >> 4;

  // stage x transposed: xT[u][e] = xg[blk*64+e][u]  (column reads, L1 absorbs)
  {
    int e = lane, u0 = wave * 16;
    const float* xr = xg + ((size_t)(blk * 64 + e)) * 64 + u0;
#pragma unroll
    for (int k = 0; k < 16; ++k) xT[(u0 + k) * 64 + e] = xr[k];
  }
  // A fragments: 4 M-tiles x 4 k-steps, register-resident (64 VGPR)
  short8 af[4][4];
#pragma unroll
  for (int mt = 0; mt < 4; ++mt)
#pragma unroll
    for (int s = 0; s < 4; ++s)
      af[mt][s] = *(const short8*)(h2s + ((size_t)((blk * 4 + mt) * 4 + s) * 64 + lane) * 8);
  __syncthreads();

  float feat[4][4] = {};               // [mt][j], this l-path only
  const u16* Bg = W2s + (size_t)(l3 * 64 + wave * 16) * 4 * 64 * 8;
  const float* b2g = b2 + (l3 * 64 + wave * 16) * 16;

#pragma unroll
  for (int k = 0; k < 16; ++k) {       // wave's 16 N-tiles, no barriers
    short8 bf[4];
#pragma unroll
    for (int s = 0; s < 4; ++s)
      bf[s] = *(const short8*)(Bg + ((k * 4 + s) * 64 + lane) * 8);
    float b2v = 0.125f * b2g[k * 16 + c];
#pragma unroll
    for (int mt = 0; mt < 4; ++mt) {
      f32x4 acc = {0.f, 0.f, 0.f, 0.f};
#pragma unroll
      for (int s = 0; s < 4; ++s)
        acc = __builtin_amdgcn_mfma_f32_16x16x32_bf16(af[mt][s], bf[s], acc, 0, 0, 0);
      const float4 xv = *(const float4*)&xT[(wave * 16 + k) * 64 + mt * 16 + g * 4];
#pragma unroll
      for (int j = 0; j < 4; ++j)
        feat[mt][j] = fmaf(xv[j], acc[j] + b2v, feat[mt][j]);
    }
  }

  // cross-wave feat reduction in LDS (reuse xT space), then single scatter
  __syncthreads();
#pragma unroll
  for (int mt = 0; mt < 4; ++mt)
#pragma unroll
    for (int j = 0; j < 4; ++j)
      fl[wave * 1040 + (mt * 16 + g * 4 + j) * 16 + c] = feat[mt][j];
  __syncthreads();

#pragma unroll
  for (int r = 0; r < 4; ++r) {
    int p = r * 256 + tid;             // (e_loc, v) pair
    int eloc = p >> 4, v = p & 15;
    int e = blk * 64 + eloc;
    if (e >= E) continue;
    float f = fl[p] + fl[1040 + p] + fl[2080 + p] + fl[3120 + p];
    float* ob = out + (size_t)dst[e] * OUTD;
    const float* sp = shb + (size_t)e * 9;
    if (l3 == 0) {
      atomicAdd(ob + v, f);
    } else if (l3 == 1) {
#pragma unroll
      for (int mm = 0; mm < 3; ++mm) atomicAdd(ob + 16 + v * 3 + mm, f * sp[1 + mm]);
    } else {
#pragma unroll
      for (int mm = 0; mm < 5; ++mm) atomicAdd(ob + 64 + v * 5 + mm, f * sp[4 + mm]);
    }
  }
}

// ---------- final mean ----------
__global__ void k_divc(float* __restrict__ out, const float* __restrict__ cnt, int total) {
  int i = blockIdx.x * 256 + threadIdx.x;
  if (i < total) out[i] /= fmaxf(cnt[i / OUTD], 1.f);
}

extern "C" void kernel_launch(void* const* d_in, const int* in_sizes, int n_in,
                              void* d_out, int out_size, void* d_ws, size_t ws_size,
                              hipStream_t stream) {
  const float* h_src        = (const float*)d_in[0];
  const float* edge_vec     = (const float*)d_in[1];
  const float* edge_scalars = (const float*)d_in[2];
  const float* W1           = (const float*)d_in[3];
  const float* b1           = (const float*)d_in[4];
  const float* W2           = (const float*)d_in[5];
  const float* b2           = (const float*)d_in[6];
  const int*   src_idx      = (const int*)d_in[7];
  const int*   dst_idx      = (const int*)d_in[8];

  const int E = in_sizes[1] / 3;
  const int n_dst = out_size / OUTD;
  const int nblk64 = (E + 63) / 64;
  const size_t E_pad = (size_t)nblk64 * 64;

  char* w = (char*)d_ws;
  auto al = [](size_t x) { return (x + 255) & ~(size_t)255; };
  size_t o = 0;
  float* xg  = (float*)(w + o);              o += al(E_pad * 64 * 4);
  float* shb = (float*)(w + o);              o += al(E_pad * 9 * 4);
  __hip_bfloat16* h2s = (__hip_bfloat16*)(w + o); o += al(E_pad * 128 * 2);
  __hip_bfloat16* W2s = (__hip_bfloat16*)(w + o); o += al((size_t)128 * 3072 * 2);
  float* cnt = (float*)(w + o);              o += al((size_t)n_dst * 4);

  hipMemsetAsync(d_out, 0, (size_t)out_size * 4, stream);
  hipMemsetAsync(cnt, 0, (size_t)n_dst * 4, stream);

  k_w2s <<<(128 * WNUMEL) / 256, 256, 0, stream>>>(W2, W2s);
  k_mlp <<<(E + 7) / 8, 256, 0, stream>>>(edge_scalars, W1, b1, h2s, E);
  k_prep<<<(E + 3) / 4, 256, 0, stream>>>(h_src, edge_vec, src_idx, dst_idx, xg, shb, cnt, E);
  dim3 gg(nblk64, 3);
  k_gemm<<<gg, 256, 0, stream>>>((const u16*)h2s, (const u16*)W2s, xg, shb, b2,
                                 dst_idx, (float*)d_out, E);
  k_divc<<<(out_size + 255) / 256, 256, 0, stream>>>((float*)d_out, cnt, out_size);
}

// Round 3
// 128.796 us; speedup vs baseline: 1.6994x; 1.6698x over previous
//
#include <hip/hip_runtime.h>
#include <hip/hip_bf16.h>

typedef unsigned short u16;
typedef __attribute__((ext_vector_type(8))) short short8;
typedef __attribute__((ext_vector_type(4))) float f32x4;

#define HID 128
#define WNUMEL 3072
#define OUTD 144

// ---------- W2 reorder: bf16, swizzled so B-fragments are lane-linear ----------
__global__ void k_w2s(const float* __restrict__ W2, __hip_bfloat16* __restrict__ W2s) {
  int t = blockIdx.x * 256 + threadIdx.x;           // < 128*3072 = 393216
  int i = t & 7, lane = (t >> 3) & 63, s = (t >> 9) & 3, tt = t >> 11;
  int c = lane & 15, h = lane >> 4;
  int k = 32 * s + 8 * h + i;
  int n = 16 * tt + c;
  W2s[t] = __float2bfloat16(W2[k * WNUMEL + n]);
}

// ---------- MLP: h2 = silu(es@W1+b1) * 0.125, stored bf16 pre-swizzled ----------
__global__ void k_mlp(const float* __restrict__ es, const float* __restrict__ W1,
                      const float* __restrict__ b1, __hip_bfloat16* __restrict__ h2s, int E) {
  __shared__ float esl[8][32];
  int tid = threadIdx.x;
  int e0 = blockIdx.x * 8;
  {
    int e = e0 + (tid >> 5);
    esl[tid >> 5][tid & 31] = (e < E) ? es[e * 32 + (tid & 31)] : 0.f;
  }
  __syncthreads();
  int h = tid & 127;
  float bh = b1[h];
#pragma unroll
  for (int r = 0; r < 4; ++r) {
    int eloc = (tid >> 7) + r * 2;
    int e = e0 + eloc;
    if (e < E) {
      float acc = bh;
#pragma unroll
      for (int i = 0; i < 32; ++i) acc = fmaf(esl[eloc][i], W1[i * HID + h], acc);
      float sg = 1.f / (1.f + expf(-acc));
      float z = acc * sg * 0.125f;                  // fold 1/sqrt(64)
      int s = h >> 5, hh = (h >> 3) & 3, i = h & 7;
      int lane = (e & 15) + 16 * hh, eblk = e >> 4;
      h2s[((size_t)(eblk * 4 + s) * 64 + lane) * 8 + i] = __float2bfloat16(z);
    }
  }
}

// ---------- prep: spherical harmonics + per-dst rank (CSR prep) ----------
__global__ void k_prep(const float* __restrict__ ev, const int* __restrict__ dst,
                       float* __restrict__ shb, int* __restrict__ cnti,
                       int* __restrict__ pos, int E) {
  int e = blockIdx.x * 256 + threadIdx.x;
  if (e >= E) return;
  float vx = ev[e * 3 + 0], vy = ev[e * 3 + 1], vz = ev[e * 3 + 2];
  float nrm = fmaxf(sqrtf(vx * vx + vy * vy + vz * vz), 1e-9f);
  float x = vx / nrm, y = vy / nrm, z = vz / nrm;
  const float SQ3 = 1.7320508075688772f, SQ5 = 2.2360679774997896f,
              SQ15 = 3.872983346207417f;
  float* sp = shb + (size_t)e * 9;
  sp[0] = 1.f;
  sp[1] = SQ3 * x; sp[2] = SQ3 * y; sp[3] = SQ3 * z;
  sp[4] = SQ15 * x * y; sp[5] = SQ15 * y * z;
  sp[6] = 0.5f * SQ5 * (3.f * z * z - 1.f);
  sp[7] = SQ15 * x * z;
  sp[8] = 0.5f * SQ15 * (x * x - y * y);
  pos[e] = atomicAdd(&cnti[dst[e]], 1);            // rank within dst bucket
}

// ---------- single-block exclusive scan: off = exscan(cnti), off[n]=E ----------
__global__ void k_scan(const int* __restrict__ cnti, int* __restrict__ off, int n, int E) {
  __shared__ int ts[1024];
  int tid = threadIdx.x;
  int m = (n + 1023) >> 10;
  int lo = tid * m, hi = min(lo + m, n);
  int s = 0;
  for (int i = lo; i < hi; ++i) s += cnti[i];
  ts[tid] = s;
  __syncthreads();
  for (int d = 1; d < 1024; d <<= 1) {
    int v = (tid >= d) ? ts[tid - d] : 0;
    __syncthreads();
    ts[tid] += v;
    __syncthreads();
  }
  int run = (tid > 0) ? ts[tid - 1] : 0;
  for (int i = lo; i < hi; ++i) { off[i] = run; run += cnti[i]; }
  if (tid == 0) off[n] = E;
}

// ---------- fill CSR edge list ----------
__global__ void k_slot(const int* __restrict__ dst, const int* __restrict__ pos,
                       const int* __restrict__ off, int* __restrict__ elist, int E) {
  int e = blockIdx.x * 256 + threadIdx.x;
  if (e < E) elist[off[dst[e]] + pos[e]] = e;
}

// ---------- fused GEMM + x-contraction + sh expand -> msg (streaming stores) ----------
// grid = (E/64, 3). 4 waves; wave w owns N-tiles [w*16, w*16+16) of l-path blockIdx.y.
// B read straight from L2 (W2s = 786 KB, resident). A-fragments register-resident.
__global__ __launch_bounds__(256, 3) void k_gemm(
    const u16* __restrict__ h2s, const u16* __restrict__ W2s,
    const float* __restrict__ hsrc, const int* __restrict__ srci,
    const float* __restrict__ shb, const float* __restrict__ b2,
    float* __restrict__ msg, int E) {
  __shared__ float lds[4160];          // xT[64u][64e] (16KB), then fl[4][1040]
  __shared__ float shl[640];           // sh staged [64e][10] (padded)
  float* xT = lds;
  float* fl = lds;
  const int tid = threadIdx.x, lane = tid & 63, wave = tid >> 6;
  const int blk = blockIdx.x, l3 = blockIdx.y;
  const int c = lane & 15, g = lane >> 4;

  // stage x transposed for THIS wave's u-range (per-wave private region)
  {
    int e = lane, u0 = wave * 16;
    int eg = min(blk * 64 + e, E - 1);
    const float* xr = hsrc + (size_t)srci[eg] * 64 + u0;
#pragma unroll
    for (int k = 0; k < 16; ++k) xT[(u0 + k) * 64 + e] = xr[k];
  }
  // stage sh for epilogue (l>=1 only)
  if (l3 > 0) {
#pragma unroll
    for (int r = 0; r < 3; ++r) {
      int idx = r * 256 + tid;
      if (idx < 576) {
        int ee = idx / 9, jj = idx - ee * 9;
        int eg = blk * 64 + ee;
        shl[ee * 10 + jj] = (eg < E) ? shb[(size_t)eg * 9 + jj] : 0.f;
      }
    }
  }
  // A fragments: 4 M-tiles x 4 k-steps, register-resident (64 VGPR)
  short8 af[4][4];
#pragma unroll
  for (int mt = 0; mt < 4; ++mt)
#pragma unroll
    for (int s = 0; s < 4; ++s)
      af[mt][s] = *(const short8*)(h2s + ((size_t)((blk * 4 + mt) * 4 + s) * 64 + lane) * 8);

  float feat[4][4] = {};               // [mt][j], this l-path, this wave's u-range
  const u16* Bg = W2s + (size_t)(l3 * 64 + wave * 16) * 4 * 64 * 8;
  const float* b2g = b2 + (l3 * 64 + wave * 16) * 16;

#pragma unroll
  for (int k = 0; k < 16; ++k) {       // wave's 16 N-tiles, no barriers
    short8 bf[4];
#pragma unroll
    for (int s = 0; s < 4; ++s)
      bf[s] = *(const short8*)(Bg + ((k * 4 + s) * 64 + lane) * 8);
    float b2v = 0.125f * b2g[k * 16 + c];
#pragma unroll
    for (int mt = 0; mt < 4; ++mt) {
      f32x4 acc = {0.f, 0.f, 0.f, 0.f};
#pragma unroll
      for (int s = 0; s < 4; ++s)
        acc = __builtin_amdgcn_mfma_f32_16x16x32_bf16(af[mt][s], bf[s], acc, 0, 0, 0);
      const float4 xv = *(const float4*)&xT[(wave * 16 + k) * 64 + mt * 16 + g * 4];
#pragma unroll
      for (int j = 0; j < 4; ++j)
        feat[mt][j] = fmaf((&xv.x)[j], acc[j] + b2v, feat[mt][j]);
    }
  }

  // cross-wave feat reduction in LDS (reuses xT space — barrier first)
  __syncthreads();
#pragma unroll
  for (int mt = 0; mt < 4; ++mt)
#pragma unroll
    for (int j = 0; j < 4; ++j)
      fl[wave * 1040 + (mt * 16 + g * 4 + j) * 16 + c] = feat[mt][j];
  __syncthreads();

  // epilogue: msg = feat (x) sh, coalesced streaming stores
  const int nel = (l3 == 0) ? 1024 : (l3 == 1) ? 3072 : 5120;
  for (int p = tid; p < nel; p += 256) {
    int eloc, v, outoff;
    float mult;
    if (l3 == 0) {
      eloc = p >> 4; v = p & 15; outoff = v; mult = 1.f;
    } else if (l3 == 1) {
      eloc = p / 48; int id = p - eloc * 48; v = id / 3; int mm = id - v * 3;
      outoff = 16 + id; mult = shl[eloc * 10 + 1 + mm];
    } else {
      eloc = p / 80; int id = p - eloc * 80; v = id / 5; int mm = id - v * 5;
      outoff = 64 + id; mult = shl[eloc * 10 + 4 + mm];
    }
    int q = eloc * 16 + v;
    float f = fl[q] + fl[1040 + q] + fl[2080 + q] + fl[3120 + q];
    int e = blk * 64 + eloc;
    if (e < E) msg[(size_t)e * OUTD + outoff] = f * mult;
  }
}

// ---------- gather: one wave per dst, mean over its edges ----------
__global__ void k_gather(const float* __restrict__ msg, const int* __restrict__ off,
                         const int* __restrict__ elist, float* __restrict__ out, int n_dst) {
  int d = blockIdx.x * 4 + (threadIdx.x >> 6);
  int lane = threadIdx.x & 63;
  if (d >= n_dst || lane >= 36) return;
  int a = off[d], b = off[d + 1];
  float4 acc = {0.f, 0.f, 0.f, 0.f};
  for (int i = a; i < b; ++i) {
    const float4 m4 = *(const float4*)&msg[(size_t)elist[i] * OUTD + lane * 4];
    acc.x += m4.x; acc.y += m4.y; acc.z += m4.z; acc.w += m4.w;
  }
  float inv = 1.f / (float)max(b - a, 1);
  acc.x *= inv; acc.y *= inv; acc.z *= inv; acc.w *= inv;
  *(float4*)&out[(size_t)d * OUTD + lane * 4] = acc;
}

extern "C" void kernel_launch(void* const* d_in, const int* in_sizes, int n_in,
                              void* d_out, int out_size, void* d_ws, size_t ws_size,
                              hipStream_t stream) {
  const float* h_src        = (const float*)d_in[0];
  const float* edge_vec     = (const float*)d_in[1];
  const float* edge_scalars = (const float*)d_in[2];
  const float* W1           = (const float*)d_in[3];
  const float* b1           = (const float*)d_in[4];
  const float* W2           = (const float*)d_in[5];
  const float* b2           = (const float*)d_in[6];
  const int*   src_idx      = (const int*)d_in[7];
  const int*   dst_idx      = (const int*)d_in[8];

  const int E = in_sizes[1] / 3;
  const int n_dst = out_size / OUTD;
  const int nblk64 = (E + 63) / 64;
  const size_t E_pad = (size_t)nblk64 * 64;

  char* w = (char*)d_ws;
  auto al = [](size_t x) { return (x + 255) & ~(size_t)255; };
  size_t o = 0;
  float* shb = (float*)(w + o);                   o += al(E_pad * 9 * 4);
  __hip_bfloat16* h2s = (__hip_bfloat16*)(w + o); o += al(E_pad * 128 * 2);
  __hip_bfloat16* W2s = (__hip_bfloat16*)(w + o); o += al((size_t)128 * 3072 * 2);
  float* msg = (float*)(w + o);                   o += al(E_pad * OUTD * 4);
  int* cnti  = (int*)(w + o);                     o += al((size_t)n_dst * 4);
  int* pos   = (int*)(w + o);                     o += al((size_t)E * 4);
  int* off   = (int*)(w + o);                     o += al((size_t)(n_dst + 1) * 4);
  int* elist = (int*)(w + o);                     o += al((size_t)E * 4);

  hipMemsetAsync(cnti, 0, (size_t)n_dst * 4, stream);

  k_w2s <<<(128 * WNUMEL) / 256, 256, 0, stream>>>(W2, W2s);
  k_mlp <<<(E + 7) / 8, 256, 0, stream>>>(edge_scalars, W1, b1, h2s, E);
  k_prep<<<(E + 255) / 256, 256, 0, stream>>>(edge_vec, dst_idx, shb, cnti, pos, E);
  k_scan<<<1, 1024, 0, stream>>>(cnti, off, n_dst, E);
  k_slot<<<(E + 255) / 256, 256, 0, stream>>>(dst_idx, pos, off, elist, E);
  dim3 gg(nblk64, 3);
  k_gemm<<<gg, 256, 0, stream>>>((const u16*)h2s, (const u16*)W2s, h_src, src_idx,
                                 shb, b2, msg, E);
  k_gather<<<(n_dst + 3) / 4, 256, 0, stream>>>(msg, off, elist, (float*)d_out, n_dst);
}